// Round 7
// baseline (807.355 us; speedup 1.0000x reference)
//
#include <hip/hip_runtime.h>
#include <hip/hip_bf16.h>

#define DI __device__ __forceinline__

typedef short bf16x8 __attribute__((ext_vector_type(8)));
typedef float f32x4 __attribute__((ext_vector_type(4)));

constexpr int BB = 8, CC = 1024, NHEAD = 16, HD = 64, HIDC = 4096, BCC = 512;
constexpr int NT = 784;            // tokens per image (28*28)
constexpr int MROWS = BB * NT;     // 6272
constexpr float ATT_SCALE = 0.125f;

DI short f2bf(float f) {
    unsigned u = __builtin_bit_cast(unsigned, f);
    u = u + 0x7FFFu + ((u >> 16) & 1u);
    return (short)(u >> 16);
}
DI float bf2f(short h) {
    unsigned u = ((unsigned)(unsigned short)h) << 16;
    return __builtin_bit_cast(float, u);
}
DI float gelu_f(float x) { return 0.5f * x * (1.0f + erff(x * 0.70710678118654752f)); }

DI void gload16(const void* g, void* l) {
    __builtin_amdgcn_global_load_lds(
        (const __attribute__((address_space(1))) void*)g,
        (__attribute__((address_space(3))) void*)l, 16, 0, 0);
}

// ---------------- transpose + f32->bf16: in[K][N] f32 -> out[N][K] bf16, 64x64 tiles ----------------
__global__ __launch_bounds__(256)
void cvt_t_kernel(const float* __restrict__ in, short* __restrict__ out, int K, int N) {
    __shared__ short t[64][68];
    const int k0 = blockIdx.y * 64, n0 = blockIdx.x * 64;
    const int tid = threadIdx.x;
    const int r = tid >> 4, c4 = (tid & 15) << 2;
    #pragma unroll
    for (int rr = 0; rr < 64; rr += 16) {
        float4 v = *(const float4*)(in + (size_t)(k0 + r + rr) * N + n0 + c4);
        t[r + rr][c4 + 0] = f2bf(v.x); t[r + rr][c4 + 1] = f2bf(v.y);
        t[r + rr][c4 + 2] = f2bf(v.z); t[r + rr][c4 + 3] = f2bf(v.w);
    }
    __syncthreads();
    #pragma unroll
    for (int rr = 0; rr < 64; rr += 16) {
        int nrow = r + rr;
        short4 o;
        o.x = t[c4 + 0][nrow]; o.y = t[c4 + 1][nrow];
        o.z = t[c4 + 2][nrow]; o.w = t[c4 + 3][nrow];
        *(short4*)(out + (size_t)(n0 + nrow) * K + k0 + c4) = o;
    }
}

// ---------------- rel-pos tables f32 -> bf16 (55*64 each) ----------------
__global__ void cvt_tables_kernel(const float* __restrict__ rph, const float* __restrict__ rpw,
                                  short* __restrict__ rhb, short* __restrict__ rwb) {
    int i = blockIdx.x * 256 + threadIdx.x;
    if (i < 3520) rhb[i] = f2bf(rph[i]);
    else if (i < 7040) rwb[i - 3520] = f2bf(rpw[i - 3520]);
}

// ---------------- LayerNorm (f32 in, bf16 or f32 out, optional GELU, optional post-LN residual) ----------------
template<bool GELU_, bool RESID, bool OUTBF>
__global__ void ln_kernel(const float* __restrict__ in, const float* __restrict__ gw,
                          const float* __restrict__ gb, const float* __restrict__ resid,
                          void* __restrict__ outv, int C, float eps) {
    const int row = blockIdx.x;
    const int tid = threadIdx.x;
    const float* x = in + (size_t)row * C;
    const int c4 = C >> 2;
    float s = 0.f, s2 = 0.f;
    for (int i = tid; i < c4; i += 256) {
        float4 v = ((const float4*)x)[i];
        s += v.x + v.y + v.z + v.w;
        s2 += v.x * v.x + v.y * v.y + v.z * v.z + v.w * v.w;
    }
    for (int off = 32; off; off >>= 1) { s += __shfl_xor(s, off); s2 += __shfl_xor(s2, off); }
    __shared__ float sa[4], sb[4], stats[2];
    int wid = tid >> 6;
    if ((tid & 63) == 0) { sa[wid] = s; sb[wid] = s2; }
    __syncthreads();
    if (tid == 0) {
        float S = sa[0] + sa[1] + sa[2] + sa[3];
        float S2 = sb[0] + sb[1] + sb[2] + sb[3];
        float mean = S / C;
        float var = S2 / C - mean * mean;
        stats[0] = mean; stats[1] = rsqrtf(var + eps);
    }
    __syncthreads();
    const float mean = stats[0], rstd = stats[1];
    for (int i = tid; i < c4; i += 256) {
        float4 v = ((const float4*)x)[i];
        float4 w4 = ((const float4*)gw)[i];
        float4 b4 = ((const float4*)gb)[i];
        float o[4] = { (v.x - mean) * rstd * w4.x + b4.x,
                       (v.y - mean) * rstd * w4.y + b4.y,
                       (v.z - mean) * rstd * w4.z + b4.z,
                       (v.w - mean) * rstd * w4.w + b4.w };
        if (GELU_) {
            #pragma unroll
            for (int j = 0; j < 4; j++) o[j] = gelu_f(o[j]);
        }
        if (RESID) {
            float4 r4 = ((const float4*)(resid + (size_t)row * C))[i];
            o[0] += r4.x; o[1] += r4.y; o[2] += r4.z; o[3] += r4.w;
        }
        if (OUTBF) {
            short4 ov; ov.x = f2bf(o[0]); ov.y = f2bf(o[1]); ov.z = f2bf(o[2]); ov.w = f2bf(o[3]);
            ((short4*)((short*)outv + (size_t)row * C))[i] = ov;
        } else {
            float4 ov; ov.x = o[0]; ov.y = o[1]; ov.z = o[2]; ov.w = o[3];
            ((float4*)((float*)outv + (size_t)row * C))[i] = ov;
        }
    }
}

// ---------------- bf16 MFMA GEMM: C[M,N] = A[M,K] * Bt[N,K]^T (+bias)(+GELU)(+resid) ----------------
// 128x128 tile, BK=32, 256 threads. Ring-4 LDS pipeline: prefetch depth 3, counted vmcnt(8)
// steady-state (2 tiles in flight across barriers), ONE s_barrier per K-tile.
// Safety: slot s (=kt&3) rewritten by stage(kt+4), issued only after barrier(kt+1) which all
// waves reach only after finishing reads of slot s; per-wave vmcnt precedes the barrier.
template<bool OUTBF, bool HASB, bool ACTG, bool HASR, bool IMC, bool DUAL>
__global__ __launch_bounds__(256)
void gemm_kernel(const short* __restrict__ A, const short* __restrict__ Bt,
                 const float* __restrict__ bias, const float* __restrict__ resid,
                 void* __restrict__ outv, short* __restrict__ out2,
                 int M, int N, int K, const short* __restrict__ zg) {
    __shared__ __align__(16) short As[4][128 * 32];
    __shared__ __align__(16) short Bs[4][128 * 32];
    const int tid = threadIdx.x;
    // bijective XCD swizzle
    const int nwg = gridDim.x * gridDim.y;
    const int orig = blockIdx.y * gridDim.x + blockIdx.x;
    const int qq = nwg >> 3, rr8 = nwg & 7;
    const int xcd = orig & 7, loc = orig >> 3;
    const int wg = (xcd < rr8 ? xcd * (qq + 1) : rr8 * (qq + 1) + (xcd - rr8) * qq) + loc;
    const int m0 = (wg / gridDim.x) * 128, n0 = (wg % gridDim.x) * 128;
    const int lane = tid & 63, wid = tid >> 6;
    const int wr = (wid >> 1) * 64, wc = (wid & 1) * 64;
    const int lr = lane & 15, lkb = lane >> 4;

    const int srow = lane >> 2;
    const int schunk = lane & 3;

    const short* aptr[2];
    const short* bptr[2];
    int sdst[2];
    int ihh[2], iww[2], ioff[2];
    const short* ibase[2];

    #pragma unroll
    for (int i = 0; i < 2; i++) {
        int seg = wid * 2 + i;
        int row = seg * 16 + srow;
        int c = schunk ^ (row & 3);
        sdst[i] = seg * 512;
        bptr[i] = Bt + (size_t)(n0 + row) * K + c * 8;
        if (!IMC) {
            aptr[i] = A + (size_t)(m0 + row) * K + c * 8;
        } else {
            int m = m0 + row;
            int bimg = m / 784, rem = m - bimg * 784;
            ihh[i] = rem / 28; iww[i] = rem - (rem / 28) * 28;
            ibase[i] = A + (size_t)bimg * 784 * 512;
            ioff[i] = c * 8;
        }
    }

    auto stage = [&](int kt) {
        const int slot = kt & 3;
        short* ab = &As[slot][0];
        short* bb = &Bs[slot][0];
        if (!IMC) {
            #pragma unroll
            for (int i = 0; i < 2; i++) {
                gload16(aptr[i] + kt * 32, ab + sdst[i]);
                gload16(bptr[i] + kt * 32, bb + sdst[i]);
            }
        } else {
            int segk = kt >> 4;
            int ky = segk / 3, kx = segk - ky * 3;
            int ccb = (kt & 15) << 5;
            #pragma unroll
            for (int i = 0; i < 2; i++) {
                int ih = ihh[i] + ky - 1, iw = iww[i] + kx - 1;
                bool ok = (ih >= 0) & (ih < 28) & (iw >= 0) & (iw < 28);
                const short* s = ok ? ibase[i] + ((size_t)(ih * 28 + iw) * 512 + ccb + ioff[i]) : zg;
                gload16(s, ab + sdst[i]);
                gload16(bptr[i] + kt * 32, bb + sdst[i]);
            }
        }
    };

    f32x4 acc[4][4];
    #pragma unroll
    for (int i = 0; i < 4; i++)
        #pragma unroll
        for (int j = 0; j < 4; j++) acc[i][j] = f32x4{0.f, 0.f, 0.f, 0.f};

    const int pc = (lkb ^ (lr & 3)) << 3;
    const int nkt = K >> 5;

    stage(0); stage(1); stage(2);
    for (int kt = 0; kt < nkt; ++kt) {
        // ensure this wave's tile-kt loads landed (keep 2 newer tiles in flight), then block-sync
        if (kt < nkt - 2)       asm volatile("s_waitcnt vmcnt(8)" ::: "memory");
        else if (kt == nkt - 2) asm volatile("s_waitcnt vmcnt(4)" ::: "memory");
        else                    asm volatile("s_waitcnt vmcnt(0)" ::: "memory");
        __builtin_amdgcn_sched_barrier(0);
        __builtin_amdgcn_s_barrier();
        __builtin_amdgcn_sched_barrier(0);
        if (kt + 3 < nkt) stage(kt + 3);
        const short* ab = &As[kt & 3][0];
        const short* bb = &Bs[kt & 3][0];
        bf16x8 af[4], bfv[4];
        #pragma unroll
        for (int mt = 0; mt < 4; mt++) af[mt] = *(const bf16x8*)&ab[(wr + mt * 16 + lr) * 32 + pc];
        #pragma unroll
        for (int nt = 0; nt < 4; nt++) bfv[nt] = *(const bf16x8*)&bb[(wc + nt * 16 + lr) * 32 + pc];
        #pragma unroll
        for (int mt = 0; mt < 4; mt++)
            #pragma unroll
            for (int nt = 0; nt < 4; nt++)
                acc[mt][nt] = __builtin_amdgcn_mfma_f32_16x16x32_bf16(af[mt], bfv[nt], acc[mt][nt], 0, 0, 0);
    }
    // epilogue: row = (lane>>4)*4+j, col = lane&15
    const int ro = (lane >> 4) << 2;
    #pragma unroll
    for (int mt = 0; mt < 4; mt++) {
        #pragma unroll
        for (int nt = 0; nt < 4; nt++) {
            int col = n0 + wc + nt * 16 + lr;
            float bv = HASB ? bias[col] : 0.0f;
            #pragma unroll
            for (int j = 0; j < 4; j++) {
                int row = m0 + wr + mt * 16 + ro + j;
                float v = acc[mt][nt][j] + bv;
                if (ACTG) v = gelu_f(v);
                size_t oi = (size_t)row * N + col;
                if (HASR) v += resid[oi];
                if (OUTBF) ((short*)outv)[oi] = f2bf(v);
                else       ((float*)outv)[oi] = v;
                if (DUAL)  out2[oi] = f2bf(v);
            }
        }
    }
}

// ---------------- decomposed rel-pos via MFMA: one wave per (pos, bh, table) ----------------
__global__ __launch_bounds__(64)
void relpos_mfma_kernel(const short* __restrict__ qkv, const short* __restrict__ rhb,
                        const short* __restrict__ rwb, float* __restrict__ relh,
                        float* __restrict__ relw) {
    const int p = blockIdx.x;        // 0..27
    const int bh = blockIdx.y;       // 0..127
    const int mode = blockIdx.z;     // 0: rel_h, 1: rel_w
    const int bimg = bh >> 4, nh = bh & 15;
    const int lane = threadIdx.x;
    const int lr = lane & 15, lkb = lane >> 4;
    const short* rb = mode ? rwb : rhb;
    float* outp = mode ? relw : relh;

    bf16x8 afr[2][2];
    #pragma unroll
    for (int mt = 0; mt < 2; mt++) {
        int kh = mt * 16 + lr;
        int sr = p - kh + 27;
        sr = sr < 0 ? 0 : (sr > 54 ? 54 : sr);
        #pragma unroll
        for (int ks = 0; ks < 2; ks++)
            afr[mt][ks] = *(const bf16x8*)(rb + sr * 64 + ks * 32 + lkb * 8);
    }
    bf16x8 bfq[2][2];
    #pragma unroll
    for (int nt = 0; nt < 2; nt++) {
        int cc = nt * 16 + lr;
        int nlin = mode ? (cc * 28 + p) : (p * 28 + cc);
        if (nlin > 783) nlin = 783;
        const short* qp = qkv + (size_t)(bimg * 784 + nlin) * 3072 + nh * 64;
        #pragma unroll
        for (int ks = 0; ks < 2; ks++)
            bfq[nt][ks] = *(const bf16x8*)(qp + ks * 32 + lkb * 8);
    }
    f32x4 acc[2][2];
    #pragma unroll
    for (int i = 0; i < 2; i++)
        #pragma unroll
        for (int j = 0; j < 2; j++) acc[i][j] = f32x4{0.f, 0.f, 0.f, 0.f};
    #pragma unroll
    for (int ks = 0; ks < 2; ks++)
        #pragma unroll
        for (int mt = 0; mt < 2; mt++)
            #pragma unroll
            for (int nt = 0; nt < 2; nt++)
                acc[mt][nt] = __builtin_amdgcn_mfma_f32_16x16x32_bf16(afr[mt][ks], bfq[nt][ks], acc[mt][nt], 0, 0, 0);
    const int ro = lkb << 2;
    #pragma unroll
    for (int nt = 0; nt < 2; nt++) {
        int cc = nt * 16 + lr;
        if (cc < 28) {
            int nlin = mode ? (cc * 28 + p) : (p * 28 + cc);
            float* o = outp + ((size_t)bh * 784 + nlin) * 28;
            *(f32x4*)(o + ro) = acc[0][nt];
            if (ro < 12) *(f32x4*)(o + 16 + ro) = acc[1][nt];
        }
    }
}

// ---------------- flash attention v2: 4 waves/block, QBLK=64, shared K/V staging ----------------
__global__ __launch_bounds__(256)
void attn_kernel(const short* __restrict__ qkv, const float* __restrict__ relh,
                 const float* __restrict__ relw, short* __restrict__ outp) {
    constexpr int VSTR = 34;
    __shared__ __align__(16) short Ks[32 * 64];      // swizzled: chunk c at row r stored at c^(r&7)
    __shared__ __align__(16) short Vt[64 * VSTR];    // Vt[d][k]
    __shared__ __align__(16) short Pl[4][16 * 40];   // per-wave P
    __shared__ float relS[4][16 * 57];               // per-wave bias rows
    const int qb = blockIdx.x;       // 0..12 (QBLK=64)
    const int bh = blockIdx.y;       // 0..127
    const int bimg = bh >> 4, nh = bh & 15;
    const int tid = threadIdx.x;
    const int lane = tid & 63, wid = tid >> 6;
    const int lr = lane & 15, lkb = lane >> 4;
    const int lk = lkb * 8;
    const int qw0 = qb * 64 + wid * 16;

    for (int idx = lane; idx < 16 * 56; idx += 64) {
        int qq = idx / 56, j = idx - qq * 56;
        int n = qw0 + qq; if (n > 783) n = 783;
        relS[wid][qq * 57 + j] = (j < 28) ? relh[((size_t)bh * 784 + n) * 28 + j]
                                          : relw[((size_t)bh * 784 + n) * 28 + (j - 28)];
    }
    bf16x8 bq0, bq1;
    {
        int tok = qw0 + lr; if (tok > 783) tok = 783;
        const short* qp = qkv + (size_t)(bimg * 784 + tok) * 3072 + nh * 64;
        bq0 = *(const bf16x8*)(qp + lk);
        bq1 = *(const bf16x8*)(qp + 32 + lk);
    }
    f32x4 oacc[4];
    #pragma unroll
    for (int i = 0; i < 4; i++) oacc[i] = f32x4{0.f, 0.f, 0.f, 0.f};
    float m_run = -1e30f, l_run = 0.0f;

    const int krow = tid >> 3, kcp = tid & 7;
    const int kclog = kcp ^ (krow & 7);
    short* kdst = Ks + wid * 512;
    const int vkey = tid & 31, vdb = tid >> 5;
    const int kq4 = lkb << 2;

    for (int kt = 0; kt < 25; ++kt) {
        const int k0 = kt * 32;
        {
            int key = k0 + krow; if (key > 783) key = 783;
            gload16(qkv + (size_t)(bimg * 784 + key) * 3072 + 1024 + nh * 64 + kclog * 8, kdst);
        }
        {
            int key = k0 + vkey; if (key > 783) key = 783;
            bf16x8 vv = *(const bf16x8*)(qkv + (size_t)(bimg * 784 + key) * 3072 + 2048 + nh * 64 + vdb * 8);
            #pragma unroll
            for (int j = 0; j < 8; j++) Vt[(vdb * 8 + j) * VSTR + vkey] = vv[j];
        }
        __syncthreads();
        f32x4 sacc[2];
        sacc[0] = f32x4{0.f, 0.f, 0.f, 0.f}; sacc[1] = f32x4{0.f, 0.f, 0.f, 0.f};
        #pragma unroll
        for (int mb = 0; mb < 2; mb++) {
            int row = mb * 16 + lr;
            bf16x8 ak0 = *(const bf16x8*)&Ks[row * 64 + ((lkb ^ (row & 7)) << 3)];
            bf16x8 ak1 = *(const bf16x8*)&Ks[row * 64 + (((4 + lkb) ^ (row & 7)) << 3)];
            sacc[mb] = __builtin_amdgcn_mfma_f32_16x16x32_bf16(ak0, bq0, sacc[mb], 0, 0, 0);
            sacc[mb] = __builtin_amdgcn_mfma_f32_16x16x32_bf16(ak1, bq1, sacc[mb], 0, 0, 0);
        }
        float sv[8];
        #pragma unroll
        for (int mb = 0; mb < 2; mb++)
            #pragma unroll
            for (int j = 0; j < 4; j++) {
                int key = k0 + mb * 16 + kq4 + j;
                float v;
                if (key < 784) {
                    int h2 = key / 28, w2 = key - (key / 28) * 28;
                    v = sacc[mb][j] * ATT_SCALE + relS[wid][lr * 57 + h2] + relS[wid][lr * 57 + 28 + w2];
                } else v = -1e30f;
                sv[mb * 4 + j] = v;
            }
        float mt_ = sv[0];
        #pragma unroll
        for (int i = 1; i < 8; i++) mt_ = fmaxf(mt_, sv[i]);
        mt_ = fmaxf(mt_, __shfl_xor(mt_, 16));
        mt_ = fmaxf(mt_, __shfl_xor(mt_, 32));
        if (__all(mt_ - m_run <= 8.0f)) {
            float psum = 0.f;
            #pragma unroll
            for (int i = 0; i < 8; i++) {
                float pz = __expf(sv[i] - m_run);
                psum += pz;
                Pl[wid][lr * 40 + ((i >> 2) * 16 + kq4 + (i & 3))] = f2bf(pz);
            }
            psum += __shfl_xor(psum, 16);
            psum += __shfl_xor(psum, 32);
            l_run += psum;
        } else {
            float mnew = fmaxf(m_run, mt_);
            float corr = __expf(m_run - mnew);
            float psum = 0.f;
            #pragma unroll
            for (int i = 0; i < 8; i++) {
                float pz = __expf(sv[i] - mnew);
                psum += pz;
                Pl[wid][lr * 40 + ((i >> 2) * 16 + kq4 + (i & 3))] = f2bf(pz);
            }
            psum += __shfl_xor(psum, 16);
            psum += __shfl_xor(psum, 32);
            l_run = l_run * corr + psum;
            m_run = mnew;
            #pragma unroll
            for (int db = 0; db < 4; db++) {
                f32x4 t = oacc[db];
                t[0] *= corr; t[1] *= corr; t[2] *= corr; t[3] *= corr;
                oacc[db] = t;
            }
        }
        bf16x8 pb = *(const bf16x8*)&Pl[wid][lr * 40 + lk];
        #pragma unroll
        for (int db = 0; db < 4; db++) {
            bf16x8 av = *(const bf16x8*)&Vt[(db * 16 + lr) * VSTR + lk];
            oacc[db] = __builtin_amdgcn_mfma_f32_16x16x32_bf16(av, pb, oacc[db], 0, 0, 0);
        }
        __syncthreads();
    }
    const float inv = 1.0f / l_run;
    const int tok = qw0 + lr;
    if (tok < 784) {
        short* op = outp + (size_t)(bimg * 784 + tok) * 1024 + nh * 64;
        #pragma unroll
        for (int db = 0; db < 4; db++)
            #pragma unroll
            for (int j = 0; j < 4; j++) {
                int d = db * 16 + kq4 + j;
                op[d] = f2bf(oacc[db][j] * inv);
            }
    }
}

// ---------------- host launch ----------------
extern "C" void kernel_launch(void* const* d_in, const int* in_sizes, int n_in,
                              void* d_out, int out_size, void* d_ws, size_t ws_size,
                              hipStream_t stream) {
    const float* x      = (const float*)d_in[0];
    const float* ln1w   = (const float*)d_in[1];
    const float* ln1b   = (const float*)d_in[2];
    const float* qkvw   = (const float*)d_in[3];
    const float* qkvbia = (const float*)d_in[4];
    const float* projw  = (const float*)d_in[5];
    const float* projb  = (const float*)d_in[6];
    const float* rph    = (const float*)d_in[7];
    const float* rpw    = (const float*)d_in[8];
    const float* ln2w   = (const float*)d_in[9];
    const float* ln2b   = (const float*)d_in[10];
    const float* m1w    = (const float*)d_in[11];
    const float* m1b    = (const float*)d_in[12];
    const float* m2w    = (const float*)d_in[13];
    const float* m2b    = (const float*)d_in[14];
    const float* c1w    = (const float*)d_in[15];
    const float* cl1w   = (const float*)d_in[16];
    const float* cl1b   = (const float*)d_in[17];
    const float* c2w    = (const float*)d_in[18];
    const float* cl2w   = (const float*)d_in[19];
    const float* cl2b   = (const float*)d_in[20];
    const float* c3w    = (const float*)d_in[21];
    const float* cl3w   = (const float*)d_in[22];
    const float* cl3b   = (const float*)d_in[23];
    float* out = (float*)d_out;

    char* base = (char*)d_ws;
    size_t off = 0;
    auto alloc = [&](size_t bytes) -> char* {
        char* p = base + off;
        off = (off + bytes + 255) & ~(size_t)255;
        return p;
    };
    short* wq  = (short*)alloc((size_t)3072 * 1024 * 2);
    short* wp  = (short*)alloc((size_t)1024 * 1024 * 2);
    short* w1  = (short*)alloc((size_t)4096 * 1024 * 2);
    short* w2  = (short*)alloc((size_t)1024 * 4096 * 2);
    short* wc1 = (short*)alloc((size_t)512 * 1024 * 2);
    short* wc2 = (short*)alloc((size_t)512 * 4608 * 2);
    short* wc3 = (short*)alloc((size_t)1024 * 512 * 2);
    short* hbuf = (short*)alloc((size_t)MROWS * 1024 * 2);
    short* qkvb = (short*)alloc((size_t)MROWS * 3072 * 2);
    float* relh = (float*)alloc((size_t)128 * 784 * 28 * 4);
    float* relw = (float*)alloc((size_t)128 * 784 * 28 * 4);
    float* xt   = (float*)alloc((size_t)MROWS * 1024 * 4);
    short* hid  = (short*)alloc((size_t)MROWS * 4096 * 2);
    float* yf   = (float*)alloc((size_t)MROWS * 1024 * 4);
    short* zg   = (short*)alloc(256);
    short* rhb  = (short*)alloc(3520 * 2);
    short* rwb  = (short*)alloc(3520 * 2);
    (void)relw; (void)ws_size; (void)in_sizes; (void)n_in; (void)out_size;

    float* o1f  = (float*)hid;
    short* o1g  = (short*)((char*)hid + (size_t)MROWS * 512 * 4);
    float* o2f  = (float*)((char*)o1g + (size_t)MROWS * 512 * 2);
    short* o2g  = (short*)((char*)o2f + (size_t)MROWS * 512 * 4);
    float* o3f  = (float*)qkvb;
    short* ybf  = (short*)relh;

    hipMemsetAsync(zg, 0, 256, stream);

    auto cvtT = [&](const float* src, short* dst, int K, int N) {
        cvt_t_kernel<<<dim3(N / 64, K / 64), 256, 0, stream>>>(src, dst, K, N);
    };
    cvtT(qkvw, wq, 1024, 3072);
    cvtT(projw, wp, 1024, 1024);
    cvtT(m1w, w1, 1024, 4096);
    cvtT(m2w, w2, 4096, 1024);
    cvtT(c1w, wc1, 1024, 512);
    cvtT(c2w, wc2, 4608, 512);
    cvtT(c3w, wc3, 512, 1024);
    cvt_tables_kernel<<<28, 256, 0, stream>>>(rph, rpw, rhb, rwb);

    ln_kernel<false, false, true><<<MROWS, 256, 0, stream>>>(x, ln1w, ln1b, nullptr, hbuf, 1024, 1e-5f);
    gemm_kernel<true, true, false, false, false, false><<<dim3(24, 49), 256, 0, stream>>>(
        hbuf, wq, qkvbia, nullptr, qkvb, nullptr, MROWS, 3072, 1024, zg);
    relpos_mfma_kernel<<<dim3(28, 128, 2), 64, 0, stream>>>(qkvb, rhb, rwb, relh, relw);
    attn_kernel<<<dim3(13, 128), 256, 0, stream>>>(qkvb, relh, relw, hbuf);
    gemm_kernel<false, true, false, true, false, false><<<dim3(8, 49), 256, 0, stream>>>(
        hbuf, wp, projb, x, xt, nullptr, MROWS, 1024, 1024, zg);
    ln_kernel<false, false, true><<<MROWS, 256, 0, stream>>>(xt, ln2w, ln2b, nullptr, hbuf, 1024, 1e-5f);
    gemm_kernel<true, true, true, false, false, false><<<dim3(32, 49), 256, 0, stream>>>(
        hbuf, w1, m1b, nullptr, hid, nullptr, MROWS, 4096, 1024, zg);
    gemm_kernel<false, true, false, true, false, true><<<dim3(8, 49), 256, 0, stream>>>(
        hid, w2, m2b, xt, yf, ybf, MROWS, 1024, 4096, zg);
    gemm_kernel<false, false, false, false, false, false><<<dim3(4, 49), 256, 0, stream>>>(
        ybf, wc1, nullptr, nullptr, o1f, nullptr, MROWS, 512, 1024, zg);
    ln_kernel<true, false, true><<<MROWS, 256, 0, stream>>>(o1f, cl1w, cl1b, nullptr, o1g, 512, 1e-6f);
    gemm_kernel<false, false, false, false, true, false><<<dim3(4, 49), 256, 0, stream>>>(
        o1g, wc2, nullptr, nullptr, o2f, nullptr, MROWS, 512, 4608, zg);
    ln_kernel<true, false, true><<<MROWS, 256, 0, stream>>>(o2f, cl2w, cl2b, nullptr, o2g, 512, 1e-6f);
    gemm_kernel<false, false, false, false, false, false><<<dim3(8, 49), 256, 0, stream>>>(
        o2g, wc3, nullptr, nullptr, o3f, nullptr, MROWS, 1024, 512, zg);
    ln_kernel<false, true, false><<<MROWS, 256, 0, stream>>>(o3f, cl3w, cl3b, yf, out, 1024, 1e-6f);
}

// Round 8
// 730.397 us; speedup vs baseline: 1.1054x; 1.1054x over previous
//
#include <hip/hip_runtime.h>
#include <hip/hip_bf16.h>

#define DI __device__ __forceinline__

typedef short bf16x8 __attribute__((ext_vector_type(8)));
typedef float f32x4 __attribute__((ext_vector_type(4)));

constexpr int BB = 8, CC = 1024, NHEAD = 16, HD = 64, HIDC = 4096, BCC = 512;
constexpr int NT = 784;            // tokens per image (28*28)
constexpr int MROWS = BB * NT;     // 6272
constexpr float ATT_SCALE = 0.125f;

DI short f2bf(float f) {
    unsigned u = __builtin_bit_cast(unsigned, f);
    u = u + 0x7FFFu + ((u >> 16) & 1u);
    return (short)(u >> 16);
}
DI float bf2f(short h) {
    unsigned u = ((unsigned)(unsigned short)h) << 16;
    return __builtin_bit_cast(float, u);
}
DI float gelu_f(float x) { return 0.5f * x * (1.0f + erff(x * 0.70710678118654752f)); }

DI void gload16(const void* g, void* l) {
    __builtin_amdgcn_global_load_lds(
        (const __attribute__((address_space(1))) void*)g,
        (__attribute__((address_space(3))) void*)l, 16, 0, 0);
}

// ---------------- transpose + f32->bf16: in[K][N] f32 -> out[N][K] bf16, 64x64 tiles ----------------
__global__ __launch_bounds__(256)
void cvt_t_kernel(const float* __restrict__ in, short* __restrict__ out, int K, int N) {
    __shared__ short t[64][68];
    const int k0 = blockIdx.y * 64, n0 = blockIdx.x * 64;
    const int tid = threadIdx.x;
    const int r = tid >> 4, c4 = (tid & 15) << 2;
    #pragma unroll
    for (int rr = 0; rr < 64; rr += 16) {
        float4 v = *(const float4*)(in + (size_t)(k0 + r + rr) * N + n0 + c4);
        t[r + rr][c4 + 0] = f2bf(v.x); t[r + rr][c4 + 1] = f2bf(v.y);
        t[r + rr][c4 + 2] = f2bf(v.z); t[r + rr][c4 + 3] = f2bf(v.w);
    }
    __syncthreads();
    #pragma unroll
    for (int rr = 0; rr < 64; rr += 16) {
        int nrow = r + rr;
        short4 o;
        o.x = t[c4 + 0][nrow]; o.y = t[c4 + 1][nrow];
        o.z = t[c4 + 2][nrow]; o.w = t[c4 + 3][nrow];
        *(short4*)(out + (size_t)(n0 + nrow) * K + k0 + c4) = o;
    }
}

// ---------------- rel-pos tables f32 -> bf16 (55*64 each) ----------------
__global__ void cvt_tables_kernel(const float* __restrict__ rph, const float* __restrict__ rpw,
                                  short* __restrict__ rhb, short* __restrict__ rwb) {
    int i = blockIdx.x * 256 + threadIdx.x;
    if (i < 3520) rhb[i] = f2bf(rph[i]);
    else if (i < 7040) rwb[i - 3520] = f2bf(rpw[i - 3520]);
}

// ---------------- LayerNorm (f32 in, bf16 or f32 out, optional GELU, optional post-LN residual) ----------------
template<bool GELU_, bool RESID, bool OUTBF>
__global__ void ln_kernel(const float* __restrict__ in, const float* __restrict__ gw,
                          const float* __restrict__ gb, const float* __restrict__ resid,
                          void* __restrict__ outv, int C, float eps) {
    const int row = blockIdx.x;
    const int tid = threadIdx.x;
    const float* x = in + (size_t)row * C;
    const int c4 = C >> 2;
    float s = 0.f, s2 = 0.f;
    for (int i = tid; i < c4; i += 256) {
        float4 v = ((const float4*)x)[i];
        s += v.x + v.y + v.z + v.w;
        s2 += v.x * v.x + v.y * v.y + v.z * v.z + v.w * v.w;
    }
    for (int off = 32; off; off >>= 1) { s += __shfl_xor(s, off); s2 += __shfl_xor(s2, off); }
    __shared__ float sa[4], sb[4], stats[2];
    int wid = tid >> 6;
    if ((tid & 63) == 0) { sa[wid] = s; sb[wid] = s2; }
    __syncthreads();
    if (tid == 0) {
        float S = sa[0] + sa[1] + sa[2] + sa[3];
        float S2 = sb[0] + sb[1] + sb[2] + sb[3];
        float mean = S / C;
        float var = S2 / C - mean * mean;
        stats[0] = mean; stats[1] = rsqrtf(var + eps);
    }
    __syncthreads();
    const float mean = stats[0], rstd = stats[1];
    for (int i = tid; i < c4; i += 256) {
        float4 v = ((const float4*)x)[i];
        float4 w4 = ((const float4*)gw)[i];
        float4 b4 = ((const float4*)gb)[i];
        float o[4] = { (v.x - mean) * rstd * w4.x + b4.x,
                       (v.y - mean) * rstd * w4.y + b4.y,
                       (v.z - mean) * rstd * w4.z + b4.z,
                       (v.w - mean) * rstd * w4.w + b4.w };
        if (GELU_) {
            #pragma unroll
            for (int j = 0; j < 4; j++) o[j] = gelu_f(o[j]);
        }
        if (RESID) {
            float4 r4 = ((const float4*)(resid + (size_t)row * C))[i];
            o[0] += r4.x; o[1] += r4.y; o[2] += r4.z; o[3] += r4.w;
        }
        if (OUTBF) {
            short4 ov; ov.x = f2bf(o[0]); ov.y = f2bf(o[1]); ov.z = f2bf(o[2]); ov.w = f2bf(o[3]);
            ((short4*)((short*)outv + (size_t)row * C))[i] = ov;
        } else {
            float4 ov; ov.x = o[0]; ov.y = o[1]; ov.z = o[2]; ov.w = o[3];
            ((float4*)((float*)outv + (size_t)row * C))[i] = ov;
        }
    }
}

// ---------------- bf16 MFMA GEMM: C[M,N] = A[M,K] * Bt[N,K]^T (+bias)(+GELU)(+resid) ----------------
// 128x128 tile, BK=32, 256 threads. 2-phase double-buffered K-loop (round-6 best: 106us, 496 TF).
// LDS kept at 32KB (5 blocks/CU) -- ring-4/64KB regressed (occupancy 5->2 blocks, m132 pattern).
template<bool OUTBF, bool HASB, bool ACTG, bool HASR, bool IMC, bool DUAL>
__global__ __launch_bounds__(256)
void gemm_kernel(const short* __restrict__ A, const short* __restrict__ Bt,
                 const float* __restrict__ bias, const float* __restrict__ resid,
                 void* __restrict__ outv, short* __restrict__ out2,
                 int M, int N, int K, const short* __restrict__ zg) {
    __shared__ __align__(16) short As[2 * 128 * 32];
    __shared__ __align__(16) short Bs[2 * 128 * 32];
    const int tid = threadIdx.x;
    // bijective XCD swizzle
    const int nwg = gridDim.x * gridDim.y;
    const int orig = blockIdx.y * gridDim.x + blockIdx.x;
    const int qq = nwg >> 3, rr8 = nwg & 7;
    const int xcd = orig & 7, loc = orig >> 3;
    const int wg = (xcd < rr8 ? xcd * (qq + 1) : rr8 * (qq + 1) + (xcd - rr8) * qq) + loc;
    const int m0 = (wg / gridDim.x) * 128, n0 = (wg % gridDim.x) * 128;
    const int lane = tid & 63, wid = tid >> 6;
    const int wr = (wid >> 1) * 64, wc = (wid & 1) * 64;
    const int lr = lane & 15, lkb = lane >> 4;

    const int srow = lane >> 2;
    const int schunk = lane & 3;

    const short* aptr[2];
    const short* bptr[2];
    int sdst[2];
    int ihh[2], iww[2], ioff[2];
    const short* ibase[2];

    #pragma unroll
    for (int i = 0; i < 2; i++) {
        int seg = wid * 2 + i;
        int row = seg * 16 + srow;
        int c = schunk ^ (row & 3);
        sdst[i] = seg * 512;
        bptr[i] = Bt + (size_t)(n0 + row) * K + c * 8;
        if (!IMC) {
            aptr[i] = A + (size_t)(m0 + row) * K + c * 8;
        } else {
            int m = m0 + row;
            int bimg = m / 784, rem = m - bimg * 784;
            ihh[i] = rem / 28; iww[i] = rem - (rem / 28) * 28;
            ibase[i] = A + (size_t)bimg * 784 * 512;
            ioff[i] = c * 8;
        }
    }

    auto stage = [&](int kt, int buf) {
        short* ab = As + buf * 4096;
        short* bb = Bs + buf * 4096;
        if (!IMC) {
            #pragma unroll
            for (int i = 0; i < 2; i++) {
                gload16(aptr[i] + kt * 32, ab + sdst[i]);
                gload16(bptr[i] + kt * 32, bb + sdst[i]);
            }
        } else {
            int segk = kt >> 4;
            int ky = segk / 3, kx = segk - ky * 3;
            int ccb = (kt & 15) << 5;
            #pragma unroll
            for (int i = 0; i < 2; i++) {
                int ih = ihh[i] + ky - 1, iw = iww[i] + kx - 1;
                bool ok = (ih >= 0) & (ih < 28) & (iw >= 0) & (iw < 28);
                const short* s = ok ? ibase[i] + ((size_t)(ih * 28 + iw) * 512 + ccb + ioff[i]) : zg;
                gload16(s, ab + sdst[i]);
                gload16(bptr[i] + kt * 32, bb + sdst[i]);
            }
        }
    };

    f32x4 acc[4][4];
    #pragma unroll
    for (int i = 0; i < 4; i++)
        #pragma unroll
        for (int j = 0; j < 4; j++) acc[i][j] = f32x4{0.f, 0.f, 0.f, 0.f};

    const int pc = (lkb ^ (lr & 3)) << 3;
    const int nkt = K >> 5;
    int cur = 0;
    stage(0, 0);
    for (int kt = 0; kt < nkt; ++kt) {
        if (kt + 1 < nkt) {
            stage(kt + 1, cur ^ 1);
            asm volatile("s_waitcnt vmcnt(4)" ::: "memory");   // tile kt complete; 4 prefetch in flight
        } else {
            asm volatile("s_waitcnt vmcnt(0)" ::: "memory");
        }
        __builtin_amdgcn_sched_barrier(0);
        __builtin_amdgcn_s_barrier();                          // tile kt visible to all waves
        __builtin_amdgcn_sched_barrier(0);
        const short* ab = As + cur * 4096;
        const short* bb = Bs + cur * 4096;
        bf16x8 af[4], bfv[4];
        #pragma unroll
        for (int mt = 0; mt < 4; mt++) af[mt] = *(const bf16x8*)&ab[(wr + mt * 16 + lr) * 32 + pc];
        #pragma unroll
        for (int nt = 0; nt < 4; nt++) bfv[nt] = *(const bf16x8*)&bb[(wc + nt * 16 + lr) * 32 + pc];
        #pragma unroll
        for (int mt = 0; mt < 4; mt++)
            #pragma unroll
            for (int nt = 0; nt < 4; nt++)
                acc[mt][nt] = __builtin_amdgcn_mfma_f32_16x16x32_bf16(af[mt], bfv[nt], acc[mt][nt], 0, 0, 0);
        __builtin_amdgcn_s_barrier();                          // all reads of buf cur done
        __builtin_amdgcn_sched_barrier(0);
        cur ^= 1;
    }
    // epilogue: row = (lane>>4)*4+j, col = lane&15
    const int ro = (lane >> 4) << 2;
    #pragma unroll
    for (int mt = 0; mt < 4; mt++) {
        #pragma unroll
        for (int nt = 0; nt < 4; nt++) {
            int col = n0 + wc + nt * 16 + lr;
            float bv = HASB ? bias[col] : 0.0f;
            #pragma unroll
            for (int j = 0; j < 4; j++) {
                int row = m0 + wr + mt * 16 + ro + j;
                float v = acc[mt][nt][j] + bv;
                if (ACTG) v = gelu_f(v);
                size_t oi = (size_t)row * N + col;
                if (HASR) v += resid[oi];
                if (OUTBF) ((short*)outv)[oi] = f2bf(v);
                else       ((float*)outv)[oi] = v;
                if (DUAL)  out2[oi] = f2bf(v);
            }
        }
    }
}

// ---------------- decomposed rel-pos via MFMA: one wave per (pos, bh, table) ----------------
__global__ __launch_bounds__(64)
void relpos_mfma_kernel(const short* __restrict__ qkv, const short* __restrict__ rhb,
                        const short* __restrict__ rwb, float* __restrict__ relh,
                        float* __restrict__ relw) {
    const int p = blockIdx.x;        // 0..27
    const int bh = blockIdx.y;       // 0..127
    const int mode = blockIdx.z;     // 0: rel_h, 1: rel_w
    const int bimg = bh >> 4, nh = bh & 15;
    const int lane = threadIdx.x;
    const int lr = lane & 15, lkb = lane >> 4;
    const short* rb = mode ? rwb : rhb;
    float* outp = mode ? relw : relh;

    bf16x8 afr[2][2];
    #pragma unroll
    for (int mt = 0; mt < 2; mt++) {
        int kh = mt * 16 + lr;
        int sr = p - kh + 27;
        sr = sr < 0 ? 0 : (sr > 54 ? 54 : sr);
        #pragma unroll
        for (int ks = 0; ks < 2; ks++)
            afr[mt][ks] = *(const bf16x8*)(rb + sr * 64 + ks * 32 + lkb * 8);
    }
    bf16x8 bfq[2][2];
    #pragma unroll
    for (int nt = 0; nt < 2; nt++) {
        int cc = nt * 16 + lr;
        int nlin = mode ? (cc * 28 + p) : (p * 28 + cc);
        if (nlin > 783) nlin = 783;
        const short* qp = qkv + (size_t)(bimg * 784 + nlin) * 3072 + nh * 64;
        #pragma unroll
        for (int ks = 0; ks < 2; ks++)
            bfq[nt][ks] = *(const bf16x8*)(qp + ks * 32 + lkb * 8);
    }
    f32x4 acc[2][2];
    #pragma unroll
    for (int i = 0; i < 2; i++)
        #pragma unroll
        for (int j = 0; j < 2; j++) acc[i][j] = f32x4{0.f, 0.f, 0.f, 0.f};
    #pragma unroll
    for (int ks = 0; ks < 2; ks++)
        #pragma unroll
        for (int mt = 0; mt < 2; mt++)
            #pragma unroll
            for (int nt = 0; nt < 2; nt++)
                acc[mt][nt] = __builtin_amdgcn_mfma_f32_16x16x32_bf16(afr[mt][ks], bfq[nt][ks], acc[mt][nt], 0, 0, 0);
    const int ro = lkb << 2;
    #pragma unroll
    for (int nt = 0; nt < 2; nt++) {
        int cc = nt * 16 + lr;
        if (cc < 28) {
            int nlin = mode ? (cc * 28 + p) : (p * 28 + cc);
            float* o = outp + ((size_t)bh * 784 + nlin) * 28;
            *(f32x4*)(o + ro) = acc[0][nt];
            if (ro < 12) *(f32x4*)(o + 16 + ro) = acc[1][nt];
        }
    }
}

// ---------------- flash attention v2: 4 waves/block, QBLK=64, shared K/V staging ----------------
// Grid (bh=128 fastest, qb=13): XCD = linear%8 = bh%8, so all 13 q-blocks of one (b,head)
// land on ONE XCD -> its 200KB K/V is fetched once into that XCD's L2 (16 heads = 3.2MB < 4MB).
__global__ __launch_bounds__(256)
void attn_kernel(const short* __restrict__ qkv, const float* __restrict__ relh,
                 const float* __restrict__ relw, short* __restrict__ outp) {
    constexpr int VSTR = 34;
    __shared__ __align__(16) short Ks[32 * 64];      // swizzled: chunk c at row r stored at c^(r&7)
    __shared__ __align__(16) short Vt[64 * VSTR];    // Vt[d][k]
    __shared__ __align__(16) short Pl[4][16 * 40];   // per-wave P
    __shared__ float relS[4][16 * 57];               // per-wave bias rows
    const int bh = blockIdx.x;       // 0..127  (fastest -> XCD = bh%8)
    const int qb = blockIdx.y;       // 0..12 (QBLK=64)
    const int bimg = bh >> 4, nh = bh & 15;
    const int tid = threadIdx.x;
    const int lane = tid & 63, wid = tid >> 6;
    const int lr = lane & 15, lkb = lane >> 4;
    const int lk = lkb * 8;
    const int qw0 = qb * 64 + wid * 16;

    for (int idx = lane; idx < 16 * 56; idx += 64) {
        int qq = idx / 56, j = idx - qq * 56;
        int n = qw0 + qq; if (n > 783) n = 783;
        relS[wid][qq * 57 + j] = (j < 28) ? relh[((size_t)bh * 784 + n) * 28 + j]
                                          : relw[((size_t)bh * 784 + n) * 28 + (j - 28)];
    }
    bf16x8 bq0, bq1;
    {
        int tok = qw0 + lr; if (tok > 783) tok = 783;
        const short* qp = qkv + (size_t)(bimg * 784 + tok) * 3072 + nh * 64;
        bq0 = *(const bf16x8*)(qp + lk);
        bq1 = *(const bf16x8*)(qp + 32 + lk);
    }
    f32x4 oacc[4];
    #pragma unroll
    for (int i = 0; i < 4; i++) oacc[i] = f32x4{0.f, 0.f, 0.f, 0.f};
    float m_run = -1e30f, l_run = 0.0f;

    const int krow = tid >> 3, kcp = tid & 7;
    const int kclog = kcp ^ (krow & 7);
    short* kdst = Ks + wid * 512;
    const int vkey = tid & 31, vdb = tid >> 5;
    const int kq4 = lkb << 2;

    for (int kt = 0; kt < 25; ++kt) {
        const int k0 = kt * 32;
        {
            int key = k0 + krow; if (key > 783) key = 783;
            gload16(qkv + (size_t)(bimg * 784 + key) * 3072 + 1024 + nh * 64 + kclog * 8, kdst);
        }
        {
            int key = k0 + vkey; if (key > 783) key = 783;
            bf16x8 vv = *(const bf16x8*)(qkv + (size_t)(bimg * 784 + key) * 3072 + 2048 + nh * 64 + vdb * 8);
            #pragma unroll
            for (int j = 0; j < 8; j++) Vt[(vdb * 8 + j) * VSTR + vkey] = vv[j];
        }
        __syncthreads();
        f32x4 sacc[2];
        sacc[0] = f32x4{0.f, 0.f, 0.f, 0.f}; sacc[1] = f32x4{0.f, 0.f, 0.f, 0.f};
        #pragma unroll
        for (int mb = 0; mb < 2; mb++) {
            int row = mb * 16 + lr;
            bf16x8 ak0 = *(const bf16x8*)&Ks[row * 64 + ((lkb ^ (row & 7)) << 3)];
            bf16x8 ak1 = *(const bf16x8*)&Ks[row * 64 + (((4 + lkb) ^ (row & 7)) << 3)];
            sacc[mb] = __builtin_amdgcn_mfma_f32_16x16x32_bf16(ak0, bq0, sacc[mb], 0, 0, 0);
            sacc[mb] = __builtin_amdgcn_mfma_f32_16x16x32_bf16(ak1, bq1, sacc[mb], 0, 0, 0);
        }
        float sv[8];
        #pragma unroll
        for (int mb = 0; mb < 2; mb++)
            #pragma unroll
            for (int j = 0; j < 4; j++) {
                int key = k0 + mb * 16 + kq4 + j;
                float v;
                if (key < 784) {
                    int h2 = key / 28, w2 = key - (key / 28) * 28;
                    v = sacc[mb][j] * ATT_SCALE + relS[wid][lr * 57 + h2] + relS[wid][lr * 57 + 28 + w2];
                } else v = -1e30f;
                sv[mb * 4 + j] = v;
            }
        float mt_ = sv[0];
        #pragma unroll
        for (int i = 1; i < 8; i++) mt_ = fmaxf(mt_, sv[i]);
        mt_ = fmaxf(mt_, __shfl_xor(mt_, 16));
        mt_ = fmaxf(mt_, __shfl_xor(mt_, 32));
        if (__all(mt_ - m_run <= 8.0f)) {
            float psum = 0.f;
            #pragma unroll
            for (int i = 0; i < 8; i++) {
                float pz = __expf(sv[i] - m_run);
                psum += pz;
                Pl[wid][lr * 40 + ((i >> 2) * 16 + kq4 + (i & 3))] = f2bf(pz);
            }
            psum += __shfl_xor(psum, 16);
            psum += __shfl_xor(psum, 32);
            l_run += psum;
        } else {
            float mnew = fmaxf(m_run, mt_);
            float corr = __expf(m_run - mnew);
            float psum = 0.f;
            #pragma unroll
            for (int i = 0; i < 8; i++) {
                float pz = __expf(sv[i] - mnew);
                psum += pz;
                Pl[wid][lr * 40 + ((i >> 2) * 16 + kq4 + (i & 3))] = f2bf(pz);
            }
            psum += __shfl_xor(psum, 16);
            psum += __shfl_xor(psum, 32);
            l_run = l_run * corr + psum;
            m_run = mnew;
            #pragma unroll
            for (int db = 0; db < 4; db++) {
                f32x4 t = oacc[db];
                t[0] *= corr; t[1] *= corr; t[2] *= corr; t[3] *= corr;
                oacc[db] = t;
            }
        }
        bf16x8 pb = *(const bf16x8*)&Pl[wid][lr * 40 + lk];
        #pragma unroll
        for (int db = 0; db < 4; db++) {
            bf16x8 av = *(const bf16x8*)&Vt[(db * 16 + lr) * VSTR + lk];
            oacc[db] = __builtin_amdgcn_mfma_f32_16x16x32_bf16(av, pb, oacc[db], 0, 0, 0);
        }
        __syncthreads();
    }
    const float inv = 1.0f / l_run;
    const int tok = qw0 + lr;
    if (tok < 784) {
        short* op = outp + (size_t)(bimg * 784 + tok) * 1024 + nh * 64;
        #pragma unroll
        for (int db = 0; db < 4; db++)
            #pragma unroll
            for (int j = 0; j < 4; j++) {
                int d = db * 16 + kq4 + j;
                op[d] = f2bf(oacc[db][j] * inv);
            }
    }
}

// ---------------- host launch ----------------
extern "C" void kernel_launch(void* const* d_in, const int* in_sizes, int n_in,
                              void* d_out, int out_size, void* d_ws, size_t ws_size,
                              hipStream_t stream) {
    const float* x      = (const float*)d_in[0];
    const float* ln1w   = (const float*)d_in[1];
    const float* ln1b   = (const float*)d_in[2];
    const float* qkvw   = (const float*)d_in[3];
    const float* qkvbia = (const float*)d_in[4];
    const float* projw  = (const float*)d_in[5];
    const float* projb  = (const float*)d_in[6];
    const float* rph    = (const float*)d_in[7];
    const float* rpw    = (const float*)d_in[8];
    const float* ln2w   = (const float*)d_in[9];
    const float* ln2b   = (const float*)d_in[10];
    const float* m1w    = (const float*)d_in[11];
    const float* m1b    = (const float*)d_in[12];
    const float* m2w    = (const float*)d_in[13];
    const float* m2b    = (const float*)d_in[14];
    const float* c1w    = (const float*)d_in[15];
    const float* cl1w   = (const float*)d_in[16];
    const float* cl1b   = (const float*)d_in[17];
    const float* c2w    = (const float*)d_in[18];
    const float* cl2w   = (const float*)d_in[19];
    const float* cl2b   = (const float*)d_in[20];
    const float* c3w    = (const float*)d_in[21];
    const float* cl3w   = (const float*)d_in[22];
    const float* cl3b   = (const float*)d_in[23];
    float* out = (float*)d_out;

    char* base = (char*)d_ws;
    size_t off = 0;
    auto alloc = [&](size_t bytes) -> char* {
        char* p = base + off;
        off = (off + bytes + 255) & ~(size_t)255;
        return p;
    };
    short* wq  = (short*)alloc((size_t)3072 * 1024 * 2);
    short* wp  = (short*)alloc((size_t)1024 * 1024 * 2);
    short* w1  = (short*)alloc((size_t)4096 * 1024 * 2);
    short* w2  = (short*)alloc((size_t)1024 * 4096 * 2);
    short* wc1 = (short*)alloc((size_t)512 * 1024 * 2);
    short* wc2 = (short*)alloc((size_t)512 * 4608 * 2);
    short* wc3 = (short*)alloc((size_t)1024 * 512 * 2);
    short* hbuf = (short*)alloc((size_t)MROWS * 1024 * 2);
    short* qkvb = (short*)alloc((size_t)MROWS * 3072 * 2);
    float* relh = (float*)alloc((size_t)128 * 784 * 28 * 4);
    float* relw = (float*)alloc((size_t)128 * 784 * 28 * 4);
    float* xt   = (float*)alloc((size_t)MROWS * 1024 * 4);
    short* hid  = (short*)alloc((size_t)MROWS * 4096 * 2);
    float* yf   = (float*)alloc((size_t)MROWS * 1024 * 4);
    short* zg   = (short*)alloc(256);
    short* rhb  = (short*)alloc(3520 * 2);
    short* rwb  = (short*)alloc(3520 * 2);
    (void)relw; (void)ws_size; (void)in_sizes; (void)n_in; (void)out_size;

    float* o1f  = (float*)hid;
    short* o1g  = (short*)((char*)hid + (size_t)MROWS * 512 * 4);
    float* o2f  = (float*)((char*)o1g + (size_t)MROWS * 512 * 2);
    short* o2g  = (short*)((char*)o2f + (size_t)MROWS * 512 * 4);
    float* o3f  = (float*)qkvb;
    short* ybf  = (short*)relh;

    hipMemsetAsync(zg, 0, 256, stream);

    auto cvtT = [&](const float* src, short* dst, int K, int N) {
        cvt_t_kernel<<<dim3(N / 64, K / 64), 256, 0, stream>>>(src, dst, K, N);
    };
    cvtT(qkvw, wq, 1024, 3072);
    cvtT(projw, wp, 1024, 1024);
    cvtT(m1w, w1, 1024, 4096);
    cvtT(m2w, w2, 4096, 1024);
    cvtT(c1w, wc1, 1024, 512);
    cvtT(c2w, wc2, 4608, 512);
    cvtT(c3w, wc3, 512, 1024);
    cvt_tables_kernel<<<28, 256, 0, stream>>>(rph, rpw, rhb, rwb);

    ln_kernel<false, false, true><<<MROWS, 256, 0, stream>>>(x, ln1w, ln1b, nullptr, hbuf, 1024, 1e-5f);
    gemm_kernel<true, true, false, false, false, false><<<dim3(24, 49), 256, 0, stream>>>(
        hbuf, wq, qkvbia, nullptr, qkvb, nullptr, MROWS, 3072, 1024, zg);
    relpos_mfma_kernel<<<dim3(28, 128, 2), 64, 0, stream>>>(qkvb, rhb, rwb, relh, relw);
    attn_kernel<<<dim3(128, 13), 256, 0, stream>>>(qkvb, relh, relw, hbuf);
    gemm_kernel<false, true, false, true, false, false><<<dim3(8, 49), 256, 0, stream>>>(
        hbuf, wp, projb, x, xt, nullptr, MROWS, 1024, 1024, zg);
    ln_kernel<false, false, true><<<MROWS, 256, 0, stream>>>(xt, ln2w, ln2b, nullptr, hbuf, 1024, 1e-5f);
    gemm_kernel<true, true, true, false, false, false><<<dim3(32, 49), 256, 0, stream>>>(
        hbuf, w1, m1b, nullptr, hid, nullptr, MROWS, 4096, 1024, zg);
    gemm_kernel<false, true, false, true, false, true><<<dim3(8, 49), 256, 0, stream>>>(
        hid, w2, m2b, xt, yf, ybf, MROWS, 1024, 4096, zg);
    gemm_kernel<false, false, false, false, false, false><<<dim3(4, 49), 256, 0, stream>>>(
        ybf, wc1, nullptr, nullptr, o1f, nullptr, MROWS, 512, 1024, zg);
    ln_kernel<true, false, true><<<MROWS, 256, 0, stream>>>(o1f, cl1w, cl1b, nullptr, o1g, 512, 1e-6f);
    gemm_kernel<false, false, false, false, true, false><<<dim3(4, 49), 256, 0, stream>>>(
        o1g, wc2, nullptr, nullptr, o2f, nullptr, MROWS, 512, 4608, zg);
    ln_kernel<true, false, true><<<MROWS, 256, 0, stream>>>(o2f, cl2w, cl2b, nullptr, o2g, 512, 1e-6f);
    gemm_kernel<false, false, false, false, false, false><<<dim3(8, 49), 256, 0, stream>>>(
        o2g, wc3, nullptr, nullptr, o3f, nullptr, MROWS, 1024, 512, zg);
    ln_kernel<false, true, false><<<MROWS, 256, 0, stream>>>(o3f, cl3w, cl3b, yf, out, 1024, 1e-6f);
}